// Round 3
// baseline (763.012 us; speedup 1.0000x reference)
//
#include <hip/hip_runtime.h>
#include <hip/hip_bf16.h>
#include <cstdint>
#include <cstddef>

typedef __hip_bfloat16 bf16;
typedef __bf16 bf16x8 __attribute__((ext_vector_type(8)));
typedef float f32x4 __attribute__((ext_vector_type(4)));

#define BB 2
#define TT 1024
#define CC 1024
#define HH 16
#define PKS 448   // floats per (bh,t) block: k[64] kk[64] bb[64] v[64] r[64] d[64] bt ct pad
#define PKB 1792  // bytes per block (448*4)
#define RING 8
#define SLOTB 2048

__device__ __forceinline__ bf16 f2b(float v){ return __float2bfloat16(v); }

// 16-lane-row sum via DPP only: xor1, xor2 (quad_perm), half_mirror (^4 after quads
// uniform), row_mirror (^8 after halves uniform). No DS pipe, no shuffles.
__device__ __forceinline__ float hex_add(float x) {
    x += __int_as_float(__builtin_amdgcn_mov_dpp(__float_as_int(x), 0xB1, 0xF, 0xF, true));  // quad_perm xor1
    x += __int_as_float(__builtin_amdgcn_mov_dpp(__float_as_int(x), 0x4E, 0xF, 0xF, true));  // quad_perm xor2
    x += __int_as_float(__builtin_amdgcn_mov_dpp(__float_as_int(x), 0x141, 0xF, 0xF, true)); // row_half_mirror (^4)
    x += __int_as_float(__builtin_amdgcn_mov_dpp(__float_as_int(x), 0x140, 0xF, 0xF, true)); // row_mirror (^8)
    return x;
}

// async global -> LDS, 16B per lane (dest = uniform base + lane*16, src per-lane)
typedef __attribute__((address_space(3))) void as3_void;
typedef __attribute__((address_space(1))) const void as1_void;
__device__ __forceinline__ void gload_lds16(const void* g, void* l) {
    __builtin_amdgcn_global_load_lds((as1_void*)g, (as3_void*)l, 16, 0, 0);
}

// ---------------- batched transpose+convert: f32 [R][S] -> bf16 [S][R] ----------------
struct TrDesc { const float* in; bf16* out; int R, S; };
struct TrArgs { TrDesc d[12]; };

__global__ __launch_bounds__(256) void transpose_batch(TrArgs args)
{
    TrDesc t = args.d[blockIdx.z];
    __shared__ float tile[32][33];
    int s0 = blockIdx.x * 32, r0 = blockIdx.y * 32;
    if (s0 >= t.S || r0 >= t.R) return;      // block-uniform early exit
    int tx = threadIdx.x & 31, ty = threadIdx.x >> 5;
#pragma unroll
    for (int i = 0; i < 4; i++) {
        int r = r0 + ty + i * 8, s = s0 + tx;
        if (r < t.R && s < t.S) tile[ty + i * 8][tx] = t.in[(size_t)r * t.S + s];
    }
    __syncthreads();
#pragma unroll
    for (int i = 0; i < 4; i++) {
        int s = s0 + ty + i * 8, r = r0 + tx;
        if (s < t.S && r < t.R) t.out[(size_t)s * t.R + r] = f2b(tile[tx][ty + i * 8]);
    }
}

// ---------------- token-shift mix (f32 in -> bf16 out) + v_first passthrough ----------------
__global__ __launch_bounds__(256) void mix_kernel(
    const float* __restrict__ x, const float* __restrict__ vfirst,
    const float* __restrict__ mr, const float* __restrict__ mw, const float* __restrict__ mk,
    const float* __restrict__ mv, const float* __restrict__ ma, const float* __restrict__ mg,
    bf16* __restrict__ xr, bf16* __restrict__ xw, bf16* __restrict__ xk,
    bf16* __restrict__ xv, bf16* __restrict__ xa, bf16* __restrict__ xg,
    float* __restrict__ vout)
{
    int row = blockIdx.x;
    int t = row & (TT - 1);
    size_t base = (size_t)row * CC;
    for (int c = threadIdx.x; c < CC; c += 256) {
        float xc = x[base + c];
        float xp = (t > 0) ? x[base - CC + c] : 0.f;
        float d = xp - xc;
        xr[base + c] = f2b(xc + d * mr[c]);
        xw[base + c] = f2b(xc + d * mw[c]);
        xk[base + c] = f2b(xc + d * mk[c]);
        xv[base + c] = f2b(xc + d * mv[c]);
        xa[base + c] = f2b(xc + d * ma[c]);
        xg[base + c] = f2b(xc + d * mg[c]);
        vout[base + c] = vfirst[base + c];   // exact f32 passthrough
    }
}

// ---------------- shared MFMA tile body: 128x128 tile of A[M,K] @ BT[N,K]^T ----------------
template <class EmitF>
__device__ __forceinline__ void gemm_tile(const bf16* __restrict__ A, const bf16* __restrict__ BT,
                                          int K, int m0, int n0, EmitF emit)
{
    __shared__ __align__(16) bf16 Atile[128 * 32];
    __shared__ __align__(16) bf16 Btile[128 * 32];
    int tid = threadIdx.x;
    int w = tid >> 6, lane = tid & 63;
    int wr = w >> 1, wc = w & 1;
    int quad = lane >> 4, l16 = lane & 15;

    f32x4 zero = {0.f, 0.f, 0.f, 0.f};
    f32x4 acc[4][4];
#pragma unroll
    for (int i = 0; i < 4; i++)
#pragma unroll
        for (int j = 0; j < 4; j++) acc[i][j] = zero;

    int rr = lane >> 2;            // 0..15
    int cs = lane & 3;             // chunk slot in LDS
    int ra0 = w * 32 + rr;         // rows this lane stages
    int ra1 = ra0 + 16;
    int cg0 = cs ^ ((ra0 >> 1) & 3);   // global chunk (XOR swizzle)
    int cg1 = cs ^ ((ra1 >> 1) & 3);

    for (int k0 = 0; k0 < K; k0 += 32) {
        uint4 av0 = *reinterpret_cast<const uint4*>(A  + (size_t)(m0 + ra0) * K + k0 + cg0 * 8);
        uint4 av1 = *reinterpret_cast<const uint4*>(A  + (size_t)(m0 + ra1) * K + k0 + cg1 * 8);
        uint4 bv0 = *reinterpret_cast<const uint4*>(BT + (size_t)(n0 + ra0) * K + k0 + cg0 * 8);
        uint4 bv1 = *reinterpret_cast<const uint4*>(BT + (size_t)(n0 + ra1) * K + k0 + cg1 * 8);
        __syncthreads();           // previous tile's reads complete
        *reinterpret_cast<uint4*>(&Atile[ra0 * 32 + cs * 8]) = av0;
        *reinterpret_cast<uint4*>(&Atile[ra1 * 32 + cs * 8]) = av1;
        *reinterpret_cast<uint4*>(&Btile[ra0 * 32 + cs * 8]) = bv0;
        *reinterpret_cast<uint4*>(&Btile[ra1 * 32 + cs * 8]) = bv1;
        __syncthreads();           // staging visible

        bf16x8 af[4], bfr[4];
#pragma unroll
        for (int mi = 0; mi < 4; mi++) {
            int m = wr * 64 + mi * 16 + l16;
            int c2 = quad ^ ((m >> 1) & 3);
            af[mi] = *reinterpret_cast<const bf16x8*>(&Atile[m * 32 + c2 * 8]);
        }
#pragma unroll
        for (int ni = 0; ni < 4; ni++) {
            int n = wc * 64 + ni * 16 + l16;
            int c2 = quad ^ ((n >> 1) & 3);
            bfr[ni] = *reinterpret_cast<const bf16x8*>(&Btile[n * 32 + c2 * 8]);
        }
#pragma unroll
        for (int mi = 0; mi < 4; mi++)
#pragma unroll
            for (int ni = 0; ni < 4; ni++)
                acc[mi][ni] = __builtin_amdgcn_mfma_f32_16x16x32_bf16(af[mi], bfr[ni], acc[mi][ni], 0, 0, 0);
    }

#pragma unroll
    for (int mi = 0; mi < 4; mi++)
#pragma unroll
        for (int ni = 0; ni < 4; ni++)
#pragma unroll
            for (int rg = 0; rg < 4; rg++) {
                int m = m0 + wr * 64 + mi * 16 + quad * 4 + rg;
                int n = n0 + wc * 64 + ni * 16 + l16;
                emit(m, n, acc[mi][ni][rg]);
            }
}

// ---------------- big projections r/k/v: z-batched, N=K=1024, f32 out ----------------
struct B3Args { const bf16* A[3]; const bf16* BT[3]; float* out[3]; };
__global__ __launch_bounds__(256) void big3_kernel(B3Args args)
{
    int z = blockIdx.z;
    float* out = args.out[z];
    gemm_tile(args.A[z], args.BT[z], 1024, blockIdx.x * 128, blockIdx.y * 128,
              [&](int m, int n, float v) { out[(size_t)m * 1024 + n] = v; });
}

// ---------------- lora stage 1: z-batched (different A per z), small N, bf16 out ----------------
struct L1Desc { const bf16* A; const bf16* BT; bf16* outB; int N; int mode; }; // mode: 0 plain, 2 tanh, 3 sigmoid
struct L1Args { L1Desc d[4]; };
__global__ __launch_bounds__(256) void lora1_kernel(L1Args args)
{
    L1Desc dz = args.d[blockIdx.z];
    gemm_tile(dz.A, dz.BT, 1024, blockIdx.x * 128, 0,
              [&](int m, int n, float v) {
                  if (n < dz.N) {
                      float r = (dz.mode == 2) ? tanhf(v)
                              : (dz.mode == 3) ? 1.f / (1.f + expf(-v)) : v;
                      dz.outB[(size_t)m * dz.N + n] = f2b(r);
                  }
              });
}

// ---------------- lora stage 2 (+g2): z-batched, N=1024, f32 out, fused epilogues ----------------
struct L2Desc { const bf16* A; const bf16* BT; const float* bias; float* outF; int K; int mode; };
struct L2Args { L2Desc d[4]; const float* vraw; const float* vfirst; };
__global__ __launch_bounds__(256) void lora2_kernel(L2Args args)
{
    L2Desc dz = args.d[blockIdx.z];
    gemm_tile(dz.A, dz.BT, dz.K, blockIdx.x * 128, blockIdx.y * 128,
              [&](int m, int n, float v) {
                  size_t idx = (size_t)m * 1024 + n;
                  if (dz.mode == 4) {
                      float xx = v + dz.bias[n];
                      float ww = -log1pf(expf(-xx)) - 0.5f;   // -softplus(-x) - 0.5
                      dz.outF[idx] = expf(-expf(ww));
                  } else if (dz.mode == 5) {
                      float xx = v + dz.bias[n];
                      dz.outF[idx] = 1.f / (1.f + expf(-xx));
                  } else if (dz.mode == 6) {
                      float gate = 1.f / (1.f + expf(-(v + dz.bias[n])));
                      float vr = args.vraw[idx];
                      dz.outF[idx] = vr + (args.vfirst[idx] - vr) * gate;
                  } else {
                      dz.outF[idx] = v;
                  }
              });
}

// ---------------- final output projection ----------------
__global__ __launch_bounds__(256) void final_kernel(const bf16* __restrict__ A, const bf16* __restrict__ BT,
                                                    float* __restrict__ out)
{
    gemm_tile(A, BT, 1024, blockIdx.x * 128, blockIdx.y * 128,
              [&](int m, int n, float v) { out[(size_t)m * 1024 + n] = v; });
}

// ---------------- pack: kk norm, k scale, r/d copy-in -> contiguous PK block per (bh,t) ----------------
// PK[bh][t] block (448 floats): k[0..63], kk[64..127], bb[128..191], v[192..255],
//                               r[256..319], d[320..383], bt@384, ct@385, pad
__global__ __launch_bounds__(256) void pack_kernel(
    float* __restrict__ k, const float* __restrict__ a, const float* __restrict__ r,
    const float* __restrict__ v, const float* __restrict__ dw,
    const float* __restrict__ kkw, const float* __restrict__ kaw,
    float* __restrict__ PK)
{
    int tid = threadIdx.x;
    int wave = tid >> 6, lane = tid & 63;
    int idx = blockIdx.x * 4 + wave;        // (b*TT+t)*HH + h
    size_t off = (size_t)idx * 64 + lane;
    int c = (idx & 15) * 64 + lane;
    float kraw = k[off];
    float av = a[off];
    float kkv = kraw * kkw[c];
    float s = kkv * kkv;
#pragma unroll
    for (int m = 32; m; m >>= 1) s += __shfl_xor(s, m);
    float kkn = kkv / fmaxf(sqrtf(s), 1e-12f);
    float ks = kraw * (1.f + (av - 1.f) * kaw[c]);
    k[off] = ks;                            // write-back for gn_kernel
    float bb = kkn * av;
    float rv = r[off];
    float dv = dw[off];
    float bt = bb * rv, ct = ks * rv;
#pragma unroll
    for (int m = 32; m; m >>= 1) { bt += __shfl_xor(bt, m); ct += __shfl_xor(ct, m); }
    int b = idx >> 14;                      // / (TT*HH)
    int h = idx & 15;
    int t = (idx >> 4) & (TT - 1);
    size_t sidx = (size_t)(b * HH + h) * TT + t;
    float* pw = PK + sidx * PKS;
    pw[lane] = ks; pw[64 + lane] = kkn; pw[128 + lane] = bb; pw[192 + lane] = v[off];
    pw[256 + lane] = rv; pw[320 + lane] = dv;
    if (lane == 0) { pw[384] = bt; pw[385] = ct; }
}

// ---------------- sequential state recurrence: LDS ring (HBM latency) + 4-set reg pipe (DS latency) ----------------
// Grid 512 = 32 bh x 16 row-blocks, XCD-grouped. Block = 1 wave, 4 rows; lane (i=lane>>4,
// c=lane&15) owns S[row][4c..4c+4) (1 f32x4 -> 23 VGPR per prefetch set, 4 sets ~ 115 total,
// no spill risk). 8-slot LDS ring staged via global_load_lds (zero VGPR cost), counted
// vmcnt(15), never 0. ds_reads are plain loads (compiler emits counted lgkm waits); ds_read
// leads its use by 3 bodies (~300cy >> 120cy DS latency). Reductions: 4 DPP-row ops.
struct SetR { f32x4 q, d, r, k, b; float vi; float2 bc; };

__device__ __forceinline__ void ds_load_set(SetR& s, const char* slot, int c16, int row)
{
    s.q  = *(const f32x4*)(slot + 256  + c16);   // kk
    s.d  = *(const f32x4*)(slot + 1280 + c16);   // decay
    s.r  = *(const f32x4*)(slot + 1024 + c16);   // r
    s.k  = *(const f32x4*)(slot + 0    + c16);   // k
    s.b  = *(const f32x4*)(slot + 512  + c16);   // bb
    s.vi = *(const float*)(slot + 768 + row * 4);
    s.bc = *(const float2*)(slot + 1536);
}

__device__ __forceinline__ float step4(const SetR& sd, f32x4& S)
{
    f32x4 Sd   = S * sd.d;
    f32x4 sacv = S * sd.q;
    f32x4 oacv = Sd * sd.r;
    float sar = (sacv[0] + sacv[1]) + (sacv[2] + sacv[3]);
    float od  = (oacv[0] + oacv[1]) + (oacv[2] + oacv[3]);
    sar = hex_add(sar);
    od  = hex_add(od);
    float sa = -sar;
    float o = fmaf(sd.vi, sd.bc.y, fmaf(sa, sd.bc.x, od));
    S = Sd + sa * sd.b + sd.vi * sd.k;
    return o;
}

__global__ __launch_bounds__(64, 1) void scan_kernel(
    const float* __restrict__ PK, float* __restrict__ ybuf)
{
    __shared__ __align__(16) char ring[RING * SLOTB];
    const int lane = threadIdx.x;
    // XCD-grouped bijective decode (grid 512 = 8 * 64): all 16 row-blocks of a head
    // land on one XCD (round-robin heuristic; correctness independent of mapping).
    const int xcd = blockIdx.x & 7, kk = blockIdx.x >> 3;
    const int bh = xcd * 4 + (kk >> 4);      // 0..31
    const int wq = kk & 15;                  // row-block 0..15
    const int b = bh >> 4, h = bh & 15;
    const int row = wq * 4 + (lane >> 4);    // 0..63
    const int c = lane & 15;
    const int c16 = c * 16;

    f32x4 S = {0.f, 0.f, 0.f, 0.f};

    const char* base = (const char*)(PK + (size_t)bh * TT * PKS);
    const char* p1 = base + lane * 16;          // bytes 0..1023 of each block
    const char* p2 = base + 1024 + lane * 16;   // bytes 1024..2047 (tail past 1792 unused)

    // prologue: stage steps 0..7, drain once (vmcnt(0) only here), preload sets 0..2
#pragma unroll
    for (int s = 0; s < RING; s++) {
        gload_lds16(p1 + (size_t)s * PKB, ring + s * SLOTB);
        gload_lds16(p2 + (size_t)s * PKB, ring + s * SLOTB + 1024);
    }
    p1 += (size_t)RING * PKB;
    p2 += (size_t)RING * PKB;
    asm volatile("s_waitcnt vmcnt(0)" ::: "memory");
    __builtin_amdgcn_sched_barrier(0);

    SetR A, B, C, D;
    ds_load_set(A, ring + 0 * SLOTB, c16, row);
    ds_load_set(B, ring + 1 * SLOTB, c16, row);
    ds_load_set(C, ring + 2 * SLOTB, c16, row);

    float* py = ybuf + (size_t)b * TT * CC + h * 64 + row;

    // body t: compute set (t&3); stage step t+8 into slot t&7; counted vmcnt so the
    // slot for step t+3 (staged 5 bodies ago) is guaranteed landed; ds_read set (t+3)&3.
    // steady state: 15 vmem ops (5 stores + 10 gloads) are younger than the required stage.
#define SCAN_BODY(SLOT, XV, PV)                                             \
    {                                                                       \
        float o = step4(XV, S);                                             \
        if (c == 0) *py = o;                                                \
        py += CC;                                                           \
        gload_lds16(p1, ring + (SLOT) * SLOTB);                             \
        gload_lds16(p2, ring + (SLOT) * SLOTB + 1024);                      \
        p1 += PKB; p2 += PKB;                                               \
        asm volatile("s_waitcnt vmcnt(15)" ::: "memory");                   \
        __builtin_amdgcn_sched_barrier(0);                                  \
        ds_load_set(PV, ring + (((SLOT) + 3) & 7) * SLOTB, c16, row);       \
    }

    for (int t = 0; t < TT; t += 8) {
        SCAN_BODY(0, A, D)
        SCAN_BODY(1, B, A)
        SCAN_BODY(2, C, B)
        SCAN_BODY(3, D, C)
        SCAN_BODY(4, A, D)
        SCAN_BODY(5, B, A)
        SCAN_BODY(6, C, B)
        SCAN_BODY(7, D, C)
    }
#undef SCAN_BODY
}

// ---------------- groupnorm + residual + gate -> z (bf16), 4 heads/block ----------------
__global__ __launch_bounds__(256) void gn_kernel(
    const float* __restrict__ y, const float* __restrict__ r, const float* __restrict__ k,
    const float* __restrict__ v, const float* __restrict__ g,
    const float* __restrict__ lnw, const float* __restrict__ lnb,
    const float* __restrict__ rk, bf16* __restrict__ z)
{
    int tid = threadIdx.x;
    int idx = blockIdx.x * 4 + (tid >> 6);   // (b*T+t)*16 + h
    int lane = tid & 63;
    size_t off = (size_t)idx * 64 + lane;
    int c = (idx & 15) * 64 + lane;
    float yv = y[off];
    float rv = r[off], kv = k[off], vv = v[off];
    float s1 = yv, s2 = yv * yv, s3 = rv * kv * rk[c];
#pragma unroll
    for (int m = 32; m; m >>= 1) {
        s1 += __shfl_xor(s1, m);
        s2 += __shfl_xor(s2, m);
        s3 += __shfl_xor(s3, m);
    }
    float mu = s1 * (1.f / 64.f);
    float var = fmaxf(s2 * (1.f / 64.f) - mu * mu, 0.f);
    float yn = (yv - mu) * rsqrtf(var + 64e-5f) * lnw[c] + lnb[c];
    float out = (yn + s3 * vv) * g[off];
    z[off] = f2b(out);
}

// ---------------- host ----------------
extern "C" void kernel_launch(void* const* d_in, const int* in_sizes, int n_in,
                              void* d_out, int out_size, void* d_ws, size_t ws_size,
                              hipStream_t stream)
{
    const float* x       = (const float*)d_in[0];
    const float* v_first = (const float*)d_in[1];
    const float* x_r = (const float*)d_in[2];
    const float* x_w = (const float*)d_in[3];
    const float* x_k = (const float*)d_in[4];
    const float* x_v = (const float*)d_in[5];
    const float* x_a = (const float*)d_in[6];
    const float* x_g = (const float*)d_in[7];
    const float* w1 = (const float*)d_in[8];
    const float* w2 = (const float*)d_in[9];
    const float* w0 = (const float*)d_in[10];
    const float* a1 = (const float*)d_in[11];
    const float* a2 = (const float*)d_in[12];
    const float* a0 = (const float*)d_in[13];
    const float* v1 = (const float*)d_in[14];
    const float* v2 = (const float*)d_in[15];
    const float* v0 = (const float*)d_in[16];
    const float* g1 = (const float*)d_in[17];
    const float* g2 = (const float*)d_in[18];
    const float* k_k = (const float*)d_in[19];
    const float* k_a = (const float*)d_in[20];
    const float* r_k = (const float*)d_in[21];
    const float* W_r = (const float*)d_in[22];
    const float* W_k = (const float*)d_in[23];
    const float* W_v = (const float*)d_in[24];
    const float* W_o = (const float*)d_in[25];
    const float* ln_w = (const float*)d_in[26];
    const float* ln_b = (const float*)d_in[27];

    const size_t BTC = (size_t)BB * TT * CC;   // 2M
    const int M = BB * TT;                     // 2048

    char* ws = (char*)d_ws;
    size_t off = 0;
    auto alloc = [&](size_t bytes) -> char* {
        char* p = ws + off;
        off += (bytes + 255) & ~(size_t)255;
        return p;
    };

    // ---- region0: everything here is dead before pack_kernel; PK aliases it ----
    bf16* xr = (bf16*)alloc(BTC * 2);
    bf16* xw = (bf16*)alloc(BTC * 2);
    bf16* xk = (bf16*)alloc(BTC * 2);
    bf16* xv = (bf16*)alloc(BTC * 2);
    bf16* xa = (bf16*)alloc(BTC * 2);
    bf16* xg = (bf16*)alloc(BTC * 2);
    bf16* WrT = (bf16*)alloc(1024 * 1024 * 2);
    bf16* WkT = (bf16*)alloc(1024 * 1024 * 2);
    bf16* WvT = (bf16*)alloc(1024 * 1024 * 2);
    bf16* w1T = (bf16*)alloc(128 * 1024 * 2);   // 64 rows used, pad benign
    bf16* a1T = (bf16*)alloc(128 * 1024 * 2);
    bf16* v1T = (bf16*)alloc(128 * 1024 * 2);   // 32 rows used
    bf16* g1T = (bf16*)alloc(128 * 1024 * 2);
    bf16* w2T = (bf16*)alloc(1024 * 64 * 2);
    bf16* a2T = (bf16*)alloc(1024 * 64 * 2);
    bf16* v2T = (bf16*)alloc(1024 * 32 * 2);
    bf16* g2T = (bf16*)alloc(1024 * 128 * 2);
    bf16* h_w = (bf16*)alloc((size_t)M * 64 * 2);
    bf16* h_a = (bf16*)alloc((size_t)M * 64 * 2);
    bf16* h_v = (bf16*)alloc((size_t)M * 32 * 2);
    bf16* h_g = (bf16*)alloc((size_t)M * 128 * 2);

    // PK aliases region0 (~57.3 MB); continue past max(region0, PK)
    float* PK = (float*)ws;
    size_t pk_end = (size_t)BB * HH * TT * PKS * 4;   // 58,720,256
    if (off < pk_end) off = pk_end;
    off = (off + 255) & ~(size_t)255;

    // ---- live across pack/scan ----
    bf16* WoT = (bf16*)alloc(1024 * 1024 * 2);
    float* rbuf = (float*)alloc(BTC * 4);
    float* kbuf = (float*)alloc(BTC * 4);
    float* vraw = (float*)alloc(BTC * 4);   // reused as ybuf after lora2
    float* vbuf = (float*)alloc(BTC * 4);
    float* dbuf = (float*)alloc(BTC * 4);   // reused as zbuf (bf16) after scan
    float* abuf = (float*)alloc(BTC * 4);
    float* gbuf = (float*)alloc(BTC * 4);

    float* ybuf = vraw;
    bf16*  zbuf = (bf16*)dbuf;

    (void)in_sizes; (void)n_in; (void)out_size; (void)ws_size;

    // 1) all weight transposes in one launch
    TrArgs ta;
    ta.d[0]  = {W_r, WrT, 1024, 1024};
    ta.d[1]  = {W_k, WkT, 1024, 1024};
    ta.d[2]  = {W_v, WvT, 1024, 1024};
    ta.d[3]  = {W_o, WoT, 1024, 1024};
    ta.d[4]  = {w1, w1T, 1024, 64};
    ta.d[5]  = {a1, a1T, 1024, 64};
    ta.d[6]  = {v1, v1T, 1024, 32};
    ta.d[7]  = {g1, g1T, 1024, 128};
    ta.d[8]  = {w2, w2T, 64, 1024};
    ta.d[9]  = {a2, a2T, 64, 1024};
    ta.d[10] = {v2, v2T, 32, 1024};
    ta.d[11] = {g2, g2T, 128, 1024};
    transpose_batch<<<dim3(32, 32, 12), 256, 0, stream>>>(ta);

    // 2) token-shift mix (+ v_first passthrough)
    float* vout = (float*)d_out + BTC;
    mix_kernel<<<BB * TT, 256, 0, stream>>>(x, v_first, x_r, x_w, x_k, x_v, x_a, x_g,
                                            xr, xw, xk, xv, xa, xg, vout);

    // 3) big projections r/k/v
    B3Args b3;
    b3.A[0] = xr; b3.A[1] = xk; b3.A[2] = xv;
    b3.BT[0] = WrT; b3.BT[1] = WkT; b3.BT[2] = WvT;
    b3.out[0] = rbuf; b3.out[1] = kbuf; b3.out[2] = vraw;
    big3_kernel<<<dim3(16, 8, 3), 256, 0, stream>>>(b3);

    // 4) lora stage 1
    L1Args l1;
    l1.d[0] = {xw, w1T, h_w, 64, 2};
    l1.d[1] = {xa, a1T, h_a, 64, 0};
    l1.d[2] = {xv, v1T, h_v, 32, 0};
    l1.d[3] = {xg, g1T, h_g, 128, 3};
    lora1_kernel<<<dim3(16, 1, 4), 256, 0, stream>>>(l1);

    // 5) lora stage 2 + g2
    L2Args l2;
    l2.d[0] = {h_w, w2T, w0, dbuf, 64, 4};
    l2.d[1] = {h_a, a2T, a0, abuf, 64, 5};
    l2.d[2] = {h_v, v2T, v0, vbuf, 32, 6};
    l2.d[3] = {h_g, g2T, nullptr, gbuf, 128, 0};
    l2.vraw = vraw; l2.vfirst = v_first;
    lora2_kernel<<<dim3(16, 8, 4), 256, 0, stream>>>(l2);

    // 6) pack (contiguous PK blocks incl. r/d/bt/ct; writes scaled k back to kbuf)
    pack_kernel<<<BB * TT * HH / 4, 256, 0, stream>>>(kbuf, abuf, rbuf, vbuf, dbuf, k_k, k_a, PK);

    // 7) sequential recurrence (LDS ring + 4-set reg pipe; 16 row-blocks per bh; writes ybuf)
    scan_kernel<<<BB * HH * 16, 64, 0, stream>>>(PK, ybuf);

    // 8) groupnorm + residual + gate (writes zbuf = dbuf region)
    gn_kernel<<<BB * TT * HH / 4, 256, 0, stream>>>(ybuf, rbuf, kbuf, vbuf, gbuf, ln_w, ln_b, r_k, zbuf);

    // 9) output projection -> d_out (f32)
    final_kernel<<<dim3(16, 8), 256, 0, stream>>>(zbuf, WoT, (float*)d_out);
}

// Round 4
// 431.693 us; speedup vs baseline: 1.7675x; 1.7675x over previous
//
#include <hip/hip_runtime.h>
#include <hip/hip_bf16.h>
#include <cstdint>
#include <cstddef>

typedef __hip_bfloat16 bf16;
typedef __bf16 bf16x8 __attribute__((ext_vector_type(8)));
typedef float f32x4 __attribute__((ext_vector_type(4)));

#define BB 2
#define TT 1024
#define CC 1024
#define HH 16
#define PKS 448   // floats per (bh,t) block: k[64] kk[64] bb[64] v[64] r[64] d[64] bt ct pad
#define PKB 1792  // bytes per block (448*4)
#define CH 8      // steps per chunk
#define NCH 4     // chunks in LDS ring
#define STEPB 2048  // bytes per step slot in LDS
#define CHB (CH * STEPB)
#define NC (TT / CH)

__device__ __forceinline__ bf16 f2b(float v){ return __float2bfloat16(v); }

// 16-lane-row sum via DPP only: xor1, xor2 (quad_perm), half_mirror (^4 after quads
// uniform), row_mirror (^8 after halves uniform). No DS pipe, no shuffles.
__device__ __forceinline__ float hex_add(float x) {
    x += __int_as_float(__builtin_amdgcn_mov_dpp(__float_as_int(x), 0xB1, 0xF, 0xF, true));  // quad_perm xor1
    x += __int_as_float(__builtin_amdgcn_mov_dpp(__float_as_int(x), 0x4E, 0xF, 0xF, true));  // quad_perm xor2
    x += __int_as_float(__builtin_amdgcn_mov_dpp(__float_as_int(x), 0x141, 0xF, 0xF, true)); // row_half_mirror (^4)
    x += __int_as_float(__builtin_amdgcn_mov_dpp(__float_as_int(x), 0x140, 0xF, 0xF, true)); // row_mirror (^8)
    return x;
}

// async global -> LDS, 16B per lane (dest = uniform base + lane*16, src per-lane)
typedef __attribute__((address_space(3))) void as3_void;
typedef __attribute__((address_space(1))) const void as1_void;
__device__ __forceinline__ void gload_lds16(const void* g, void* l) {
    __builtin_amdgcn_global_load_lds((as1_void*)g, (as3_void*)l, 16, 0, 0);
}

// ---------------- batched transpose+convert: f32 [R][S] -> bf16 [S][R] ----------------
struct TrDesc { const float* in; bf16* out; int R, S; };
struct TrArgs { TrDesc d[12]; };

__global__ __launch_bounds__(256) void transpose_batch(TrArgs args)
{
    TrDesc t = args.d[blockIdx.z];
    __shared__ float tile[32][33];
    int s0 = blockIdx.x * 32, r0 = blockIdx.y * 32;
    if (s0 >= t.S || r0 >= t.R) return;      // block-uniform early exit
    int tx = threadIdx.x & 31, ty = threadIdx.x >> 5;
#pragma unroll
    for (int i = 0; i < 4; i++) {
        int r = r0 + ty + i * 8, s = s0 + tx;
        if (r < t.R && s < t.S) tile[ty + i * 8][tx] = t.in[(size_t)r * t.S + s];
    }
    __syncthreads();
#pragma unroll
    for (int i = 0; i < 4; i++) {
        int s = s0 + ty + i * 8, r = r0 + tx;
        if (s < t.S && r < t.R) t.out[(size_t)s * t.R + r] = f2b(tile[tx][ty + i * 8]);
    }
}

// ---------------- token-shift mix (f32 in -> bf16 out) + v_first passthrough ----------------
__global__ __launch_bounds__(256) void mix_kernel(
    const float* __restrict__ x, const float* __restrict__ vfirst,
    const float* __restrict__ mr, const float* __restrict__ mw, const float* __restrict__ mk,
    const float* __restrict__ mv, const float* __restrict__ ma, const float* __restrict__ mg,
    bf16* __restrict__ xr, bf16* __restrict__ xw, bf16* __restrict__ xk,
    bf16* __restrict__ xv, bf16* __restrict__ xa, bf16* __restrict__ xg,
    float* __restrict__ vout)
{
    int row = blockIdx.x;
    int t = row & (TT - 1);
    size_t base = (size_t)row * CC;
    for (int c = threadIdx.x; c < CC; c += 256) {
        float xc = x[base + c];
        float xp = (t > 0) ? x[base - CC + c] : 0.f;
        float d = xp - xc;
        xr[base + c] = f2b(xc + d * mr[c]);
        xw[base + c] = f2b(xc + d * mw[c]);
        xk[base + c] = f2b(xc + d * mk[c]);
        xv[base + c] = f2b(xc + d * mv[c]);
        xa[base + c] = f2b(xc + d * ma[c]);
        xg[base + c] = f2b(xc + d * mg[c]);
        vout[base + c] = vfirst[base + c];   // exact f32 passthrough
    }
}

// ---------------- shared MFMA tile body: 128x128 tile of A[M,K] @ BT[N,K]^T ----------------
template <class EmitF>
__device__ __forceinline__ void gemm_tile(const bf16* __restrict__ A, const bf16* __restrict__ BT,
                                          int K, int m0, int n0, EmitF emit)
{
    __shared__ __align__(16) bf16 Atile[128 * 32];
    __shared__ __align__(16) bf16 Btile[128 * 32];
    int tid = threadIdx.x;
    int w = tid >> 6, lane = tid & 63;
    int wr = w >> 1, wc = w & 1;
    int quad = lane >> 4, l16 = lane & 15;

    f32x4 zero = {0.f, 0.f, 0.f, 0.f};
    f32x4 acc[4][4];
#pragma unroll
    for (int i = 0; i < 4; i++)
#pragma unroll
        for (int j = 0; j < 4; j++) acc[i][j] = zero;

    int rr = lane >> 2;            // 0..15
    int cs = lane & 3;             // chunk slot in LDS
    int ra0 = w * 32 + rr;         // rows this lane stages
    int ra1 = ra0 + 16;
    int cg0 = cs ^ ((ra0 >> 1) & 3);   // global chunk (XOR swizzle)
    int cg1 = cs ^ ((ra1 >> 1) & 3);

    for (int k0 = 0; k0 < K; k0 += 32) {
        uint4 av0 = *reinterpret_cast<const uint4*>(A  + (size_t)(m0 + ra0) * K + k0 + cg0 * 8);
        uint4 av1 = *reinterpret_cast<const uint4*>(A  + (size_t)(m0 + ra1) * K + k0 + cg1 * 8);
        uint4 bv0 = *reinterpret_cast<const uint4*>(BT + (size_t)(n0 + ra0) * K + k0 + cg0 * 8);
        uint4 bv1 = *reinterpret_cast<const uint4*>(BT + (size_t)(n0 + ra1) * K + k0 + cg1 * 8);
        __syncthreads();           // previous tile's reads complete
        *reinterpret_cast<uint4*>(&Atile[ra0 * 32 + cs * 8]) = av0;
        *reinterpret_cast<uint4*>(&Atile[ra1 * 32 + cs * 8]) = av1;
        *reinterpret_cast<uint4*>(&Btile[ra0 * 32 + cs * 8]) = bv0;
        *reinterpret_cast<uint4*>(&Btile[ra1 * 32 + cs * 8]) = bv1;
        __syncthreads();           // staging visible

        bf16x8 af[4], bfr[4];
#pragma unroll
        for (int mi = 0; mi < 4; mi++) {
            int m = wr * 64 + mi * 16 + l16;
            int c2 = quad ^ ((m >> 1) & 3);
            af[mi] = *reinterpret_cast<const bf16x8*>(&Atile[m * 32 + c2 * 8]);
        }
#pragma unroll
        for (int ni = 0; ni < 4; ni++) {
            int n = wc * 64 + ni * 16 + l16;
            int c2 = quad ^ ((n >> 1) & 3);
            bfr[ni] = *reinterpret_cast<const bf16x8*>(&Btile[n * 32 + c2 * 8]);
        }
#pragma unroll
        for (int mi = 0; mi < 4; mi++)
#pragma unroll
            for (int ni = 0; ni < 4; ni++)
                acc[mi][ni] = __builtin_amdgcn_mfma_f32_16x16x32_bf16(af[mi], bfr[ni], acc[mi][ni], 0, 0, 0);
    }

#pragma unroll
    for (int mi = 0; mi < 4; mi++)
#pragma unroll
        for (int ni = 0; ni < 4; ni++)
#pragma unroll
            for (int rg = 0; rg < 4; rg++) {
                int m = m0 + wr * 64 + mi * 16 + quad * 4 + rg;
                int n = n0 + wc * 64 + ni * 16 + l16;
                emit(m, n, acc[mi][ni][rg]);
            }
}

// ---------------- big projections r/k/v: z-batched, N=K=1024, f32 out ----------------
struct B3Args { const bf16* A[3]; const bf16* BT[3]; float* out[3]; };
__global__ __launch_bounds__(256) void big3_kernel(B3Args args)
{
    int z = blockIdx.z;
    float* out = args.out[z];
    gemm_tile(args.A[z], args.BT[z], 1024, blockIdx.x * 128, blockIdx.y * 128,
              [&](int m, int n, float v) { out[(size_t)m * 1024 + n] = v; });
}

// ---------------- lora stage 1: z-batched (different A per z), small N, bf16 out ----------------
struct L1Desc { const bf16* A; const bf16* BT; bf16* outB; int N; int mode; }; // mode: 0 plain, 2 tanh, 3 sigmoid
struct L1Args { L1Desc d[4]; };
__global__ __launch_bounds__(256) void lora1_kernel(L1Args args)
{
    L1Desc dz = args.d[blockIdx.z];
    gemm_tile(dz.A, dz.BT, 1024, blockIdx.x * 128, 0,
              [&](int m, int n, float v) {
                  if (n < dz.N) {
                      float r = (dz.mode == 2) ? tanhf(v)
                              : (dz.mode == 3) ? 1.f / (1.f + expf(-v)) : v;
                      dz.outB[(size_t)m * dz.N + n] = f2b(r);
                  }
              });
}

// ---------------- lora stage 2 (+g2): z-batched, N=1024, f32 out, fused epilogues ----------------
struct L2Desc { const bf16* A; const bf16* BT; const float* bias; float* outF; int K; int mode; };
struct L2Args { L2Desc d[4]; const float* vraw; const float* vfirst; };
__global__ __launch_bounds__(256) void lora2_kernel(L2Args args)
{
    L2Desc dz = args.d[blockIdx.z];
    gemm_tile(dz.A, dz.BT, dz.K, blockIdx.x * 128, blockIdx.y * 128,
              [&](int m, int n, float v) {
                  size_t idx = (size_t)m * 1024 + n;
                  if (dz.mode == 4) {
                      float xx = v + dz.bias[n];
                      float ww = -log1pf(expf(-xx)) - 0.5f;   // -softplus(-x) - 0.5
                      dz.outF[idx] = expf(-expf(ww));
                  } else if (dz.mode == 5) {
                      float xx = v + dz.bias[n];
                      dz.outF[idx] = 1.f / (1.f + expf(-xx));
                  } else if (dz.mode == 6) {
                      float gate = 1.f / (1.f + expf(-(v + dz.bias[n])));
                      float vr = args.vraw[idx];
                      dz.outF[idx] = vr + (args.vfirst[idx] - vr) * gate;
                  } else {
                      dz.outF[idx] = v;
                  }
              });
}

// ---------------- final output projection ----------------
__global__ __launch_bounds__(256) void final_kernel(const bf16* __restrict__ A, const bf16* __restrict__ BT,
                                                    float* __restrict__ out)
{
    gemm_tile(A, BT, 1024, blockIdx.x * 128, blockIdx.y * 128,
              [&](int m, int n, float v) { out[(size_t)m * 1024 + n] = v; });
}

// ---------------- pack: kk norm, k scale, r/d copy-in -> contiguous PK block per (bh,t) ----------------
// PK[bh][t] block (448 floats): k[0..63], kk[64..127], bb[128..191], v[192..255],
//                               r[256..319], d[320..383], bt@384, ct@385, pad
__global__ __launch_bounds__(256) void pack_kernel(
    float* __restrict__ k, const float* __restrict__ a, const float* __restrict__ r,
    const float* __restrict__ v, const float* __restrict__ dw,
    const float* __restrict__ kkw, const float* __restrict__ kaw,
    float* __restrict__ PK)
{
    int tid = threadIdx.x;
    int wave = tid >> 6, lane = tid & 63;
    int idx = blockIdx.x * 4 + wave;        // (b*TT+t)*HH + h
    size_t off = (size_t)idx * 64 + lane;
    int c = (idx & 15) * 64 + lane;
    float kraw = k[off];
    float av = a[off];
    float kkv = kraw * kkw[c];
    float s = kkv * kkv;
#pragma unroll
    for (int m = 32; m; m >>= 1) s += __shfl_xor(s, m);
    float kkn = kkv / fmaxf(sqrtf(s), 1e-12f);
    float ks = kraw * (1.f + (av - 1.f) * kaw[c]);
    k[off] = ks;                            // write-back for gn_kernel
    float bb = kkn * av;
    float rv = r[off];
    float dv = dw[off];
    float bt = bb * rv, ct = ks * rv;
#pragma unroll
    for (int m = 32; m; m >>= 1) { bt += __shfl_xor(bt, m); ct += __shfl_xor(ct, m); }
    int b = idx >> 14;                      // / (TT*HH)
    int h = idx & 15;
    int t = (idx >> 4) & (TT - 1);
    size_t sidx = (size_t)(b * HH + h) * TT + t;
    float* pw = PK + sidx * PKS;
    pw[lane] = ks; pw[64 + lane] = kkn; pw[128 + lane] = bb; pw[192 + lane] = v[off];
    pw[256 + lane] = rv; pw[320 + lane] = dv;
    if (lane == 0) { pw[384] = bt; pw[385] = ct; }
}

// ---------------- sequential state recurrence: producer/consumer waves ----------------
// Grid 512 = 32 bh x 16 row-blocks (XCD-grouped). Block = 256 threads = 4 waves:
// wave 0 computes, waves 1-3 stage 8-step chunks into a 4-chunk LDS ring via
// global_load_lds (3 chunks ahead). __syncthreads() once per chunk: its implicit
// per-wave vmcnt/lgkm drain gives producer->consumer visibility with no hand waits.
// Compute wave: lane (i=lane>>4, c=lane&15) owns S[row0+i][4c..4c+4); per step
// 7 ds_reads (prefetched 1 step ahead, 2-set reg pipe) + ~30 VALU; DPP-only reduce.
struct SetR { f32x4 q, d, r, k, b; float vi; float2 bc; };

__device__ __forceinline__ void ds_load_set(SetR& s, const char* slot, int c16, int row)
{
    s.q  = *(const f32x4*)(slot + 256  + c16);   // kk
    s.d  = *(const f32x4*)(slot + 1280 + c16);   // decay
    s.r  = *(const f32x4*)(slot + 1024 + c16);   // r
    s.k  = *(const f32x4*)(slot + 0    + c16);   // k
    s.b  = *(const f32x4*)(slot + 512  + c16);   // bb
    s.vi = *(const float*)(slot + 768 + row * 4);
    s.bc = *(const float2*)(slot + 1536);
}

__device__ __forceinline__ float step4(const SetR& sd, f32x4& S)
{
    f32x4 Sd   = S * sd.d;
    f32x4 sacv = S * sd.q;
    f32x4 oacv = Sd * sd.r;
    float sar = (sacv[0] + sacv[1]) + (sacv[2] + sacv[3]);
    float od  = (oacv[0] + oacv[1]) + (oacv[2] + oacv[3]);
    sar = hex_add(sar);
    od  = hex_add(od);
    float sa = -sar;
    float o = fmaf(sd.vi, sd.bc.y, fmaf(sa, sd.bc.x, od));
    S = Sd + sa * sd.b + sd.vi * sd.k;
    return o;
}

__global__ __launch_bounds__(256, 1) void scan_kernel(
    const float* __restrict__ PK, float* __restrict__ ybuf)
{
    __shared__ __align__(16) char ring[NCH * CHB];   // 4 chunks x 8 steps x 2KB = 64KB
    const int tid = threadIdx.x;
    const int wid = tid >> 6, lane = tid & 63;
    // XCD-grouped bijective decode (grid 512): all 16 row-blocks of a head on one XCD.
    const int xcd = blockIdx.x & 7, kk = blockIdx.x >> 3;
    const int bh = xcd * 4 + (kk >> 4);      // 0..31
    const int wq = kk & 15;                  // row-block 0..15
    const int b = bh >> 4, h = bh & 15;
    const int row = wq * 4 + (lane >> 4);    // 0..63 (compute wave semantics)
    const int c = lane & 15;
    const int c16 = c * 16;

    const char* base = (const char*)(PK + (size_t)bh * TT * PKS);
    const char* g1 = base + lane * 16;          // bytes 0..1023 of each step block
    const char* g2 = g1 + 1024;                 // bytes 1024..2047 (tail waste benign)

    // loader lambda: wave wid (1..3) stages steps j = wid-1, wid-1+3, ... of chunk ci
    auto stage_chunk = [&](int ci) {
        const char* p1 = g1 + (size_t)ci * CH * PKB;
        const char* p2 = g2 + (size_t)ci * CH * PKB;
        char* s = ring + (ci & (NCH - 1)) * CHB;
        for (int j = wid - 1; j < CH; j += 3) {
            gload_lds16(p1 + (size_t)j * PKB, s + j * STEPB);
            gload_lds16(p2 + (size_t)j * PKB, s + j * STEPB + 1024);
        }
    };

    if (wid > 0) {
        stage_chunk(0);
        stage_chunk(1);
        stage_chunk(2);
    }
    __syncthreads();                          // drains loaders' vmcnt; chunks 0-2 visible

    f32x4 S = {0.f, 0.f, 0.f, 0.f};
    SetR X, Y;
    if (wid == 0) ds_load_set(X, ring, c16, row);
    float* py = ybuf + (size_t)b * TT * CC + h * 64 + row;

    for (int i = 0; i < NC; i++) {
        if (wid == 0) {
            const char* sl  = ring + (i & (NCH - 1)) * CHB;
            const char* sln = ring + ((i + 1) & (NCH - 1)) * CHB;
            float o;
            // 8 steps, 2-set pipe: load next step's set, compute current.
            ds_load_set(Y, sl + 1 * STEPB, c16, row); o = step4(X, S); if (c == 0) *py = o; py += CC;
            ds_load_set(X, sl + 2 * STEPB, c16, row); o = step4(Y, S); if (c == 0) *py = o; py += CC;
            ds_load_set(Y, sl + 3 * STEPB, c16, row); o = step4(X, S); if (c == 0) *py = o; py += CC;
            ds_load_set(X, sl + 4 * STEPB, c16, row); o = step4(Y, S); if (c == 0) *py = o; py += CC;
            ds_load_set(Y, sl + 5 * STEPB, c16, row); o = step4(X, S); if (c == 0) *py = o; py += CC;
            ds_load_set(X, sl + 6 * STEPB, c16, row); o = step4(Y, S); if (c == 0) *py = o; py += CC;
            ds_load_set(Y, sl + 7 * STEPB, c16, row); o = step4(X, S); if (c == 0) *py = o; py += CC;
            ds_load_set(X, sln,            c16, row); o = step4(Y, S); if (c == 0) *py = o; py += CC;
            // (i == NC-1: the final ds_load_set reads stale slot data, never consumed)
        } else {
            if (i + 3 < NC) stage_chunk(i + 3);
        }
        __syncthreads();   // loaders: implicit vmcnt(0) publishes chunk i+3; compute: done with chunk i
    }
}

// ---------------- groupnorm + residual + gate -> z (bf16), 4 heads/block ----------------
__global__ __launch_bounds__(256) void gn_kernel(
    const float* __restrict__ y, const float* __restrict__ r, const float* __restrict__ k,
    const float* __restrict__ v, const float* __restrict__ g,
    const float* __restrict__ lnw, const float* __restrict__ lnb,
    const float* __restrict__ rk, bf16* __restrict__ z)
{
    int tid = threadIdx.x;
    int idx = blockIdx.x * 4 + (tid >> 6);   // (b*T+t)*16 + h
    int lane = tid & 63;
    size_t off = (size_t)idx * 64 + lane;
    int c = (idx & 15) * 64 + lane;
    float yv = y[off];
    float rv = r[off], kv = k[off], vv = v[off];
    float s1 = yv, s2 = yv * yv, s3 = rv * kv * rk[c];
#pragma unroll
    for (int m = 32; m; m >>= 1) {
        s1 += __shfl_xor(s1, m);
        s2 += __shfl_xor(s2, m);
        s3 += __shfl_xor(s3, m);
    }
    float mu = s1 * (1.f / 64.f);
    float var = fmaxf(s2 * (1.f / 64.f) - mu * mu, 0.f);
    float yn = (yv - mu) * rsqrtf(var + 64e-5f) * lnw[c] + lnb[c];
    float out = (yn + s3 * vv) * g[off];
    z[off] = f2b(out);
}

// ---------------- host ----------------
extern "C" void kernel_launch(void* const* d_in, const int* in_sizes, int n_in,
                              void* d_out, int out_size, void* d_ws, size_t ws_size,
                              hipStream_t stream)
{
    const float* x       = (const float*)d_in[0];
    const float* v_first = (const float*)d_in[1];
    const float* x_r = (const float*)d_in[2];
    const float* x_w = (const float*)d_in[3];
    const float* x_k = (const float*)d_in[4];
    const float* x_v = (const float*)d_in[5];
    const float* x_a = (const float*)d_in[6];
    const float* x_g = (const float*)d_in[7];
    const float* w1 = (const float*)d_in[8];
    const float* w2 = (const float*)d_in[9];
    const float* w0 = (const float*)d_in[10];
    const float* a1 = (const float*)d_in[11];
    const float* a2 = (const float*)d_in[12];
    const float* a0 = (const float*)d_in[13];
    const float* v1 = (const float*)d_in[14];
    const float* v2 = (const float*)d_in[15];
    const float* v0 = (const float*)d_in[16];
    const float* g1 = (const float*)d_in[17];
    const float* g2 = (const float*)d_in[18];
    const float* k_k = (const float*)d_in[19];
    const float* k_a = (const float*)d_in[20];
    const float* r_k = (const float*)d_in[21];
    const float* W_r = (const float*)d_in[22];
    const float* W_k = (const float*)d_in[23];
    const float* W_v = (const float*)d_in[24];
    const float* W_o = (const float*)d_in[25];
    const float* ln_w = (const float*)d_in[26];
    const float* ln_b = (const float*)d_in[27];

    const size_t BTC = (size_t)BB * TT * CC;   // 2M
    const int M = BB * TT;                     // 2048

    char* ws = (char*)d_ws;
    size_t off = 0;
    auto alloc = [&](size_t bytes) -> char* {
        char* p = ws + off;
        off += (bytes + 255) & ~(size_t)255;
        return p;
    };

    // ---- region0: everything here is dead before pack_kernel; PK aliases it ----
    bf16* xr = (bf16*)alloc(BTC * 2);
    bf16* xw = (bf16*)alloc(BTC * 2);
    bf16* xk = (bf16*)alloc(BTC * 2);
    bf16* xv = (bf16*)alloc(BTC * 2);
    bf16* xa = (bf16*)alloc(BTC * 2);
    bf16* xg = (bf16*)alloc(BTC * 2);
    bf16* WrT = (bf16*)alloc(1024 * 1024 * 2);
    bf16* WkT = (bf16*)alloc(1024 * 1024 * 2);
    bf16* WvT = (bf16*)alloc(1024 * 1024 * 2);
    bf16* w1T = (bf16*)alloc(128 * 1024 * 2);   // 64 rows used, pad benign
    bf16* a1T = (bf16*)alloc(128 * 1024 * 2);
    bf16* v1T = (bf16*)alloc(128 * 1024 * 2);   // 32 rows used
    bf16* g1T = (bf16*)alloc(128 * 1024 * 2);
    bf16* w2T = (bf16*)alloc(1024 * 64 * 2);
    bf16* a2T = (bf16*)alloc(1024 * 64 * 2);
    bf16* v2T = (bf16*)alloc(1024 * 32 * 2);
    bf16* g2T = (bf16*)alloc(1024 * 128 * 2);
    bf16* h_w = (bf16*)alloc((size_t)M * 64 * 2);
    bf16* h_a = (bf16*)alloc((size_t)M * 64 * 2);
    bf16* h_v = (bf16*)alloc((size_t)M * 32 * 2);
    bf16* h_g = (bf16*)alloc((size_t)M * 128 * 2);

    // PK aliases region0 (~57.3 MB); continue past max(region0, PK)
    float* PK = (float*)ws;
    size_t pk_end = (size_t)BB * HH * TT * PKS * 4;   // 58,720,256
    if (off < pk_end) off = pk_end;
    off = (off + 255) & ~(size_t)255;

    // ---- live across pack/scan ----
    bf16* WoT = (bf16*)alloc(1024 * 1024 * 2);
    float* rbuf = (float*)alloc(BTC * 4);
    float* kbuf = (float*)alloc(BTC * 4);
    float* vraw = (float*)alloc(BTC * 4);   // reused as ybuf after lora2
    float* vbuf = (float*)alloc(BTC * 4);
    float* dbuf = (float*)alloc(BTC * 4);   // reused as zbuf (bf16) after scan
    float* abuf = (float*)alloc(BTC * 4);
    float* gbuf = (float*)alloc(BTC * 4);

    float* ybuf = vraw;
    bf16*  zbuf = (bf16*)dbuf;

    (void)in_sizes; (void)n_in; (void)out_size; (void)ws_size;

    // 1) all weight transposes in one launch
    TrArgs ta;
    ta.d[0]  = {W_r, WrT, 1024, 1024};
    ta.d[1]  = {W_k, WkT, 1024, 1024};
    ta.d[2]  = {W_v, WvT, 1024, 1024};
    ta.d[3]  = {W_o, WoT, 1024, 1024};
    ta.d[4]  = {w1, w1T, 1024, 64};
    ta.d[5]  = {a1, a1T, 1024, 64};
    ta.d[6]  = {v1, v1T, 1024, 32};
    ta.d[7]  = {g1, g1T, 1024, 128};
    ta.d[8]  = {w2, w2T, 64, 1024};
    ta.d[9]  = {a2, a2T, 64, 1024};
    ta.d[10] = {v2, v2T, 32, 1024};
    ta.d[11] = {g2, g2T, 128, 1024};
    transpose_batch<<<dim3(32, 32, 12), 256, 0, stream>>>(ta);

    // 2) token-shift mix (+ v_first passthrough)
    float* vout = (float*)d_out + BTC;
    mix_kernel<<<BB * TT, 256, 0, stream>>>(x, v_first, x_r, x_w, x_k, x_v, x_a, x_g,
                                            xr, xw, xk, xv, xa, xg, vout);

    // 3) big projections r/k/v
    B3Args b3;
    b3.A[0] = xr; b3.A[1] = xk; b3.A[2] = xv;
    b3.BT[0] = WrT; b3.BT[1] = WkT; b3.BT[2] = WvT;
    b3.out[0] = rbuf; b3.out[1] = kbuf; b3.out[2] = vraw;
    big3_kernel<<<dim3(16, 8, 3), 256, 0, stream>>>(b3);

    // 4) lora stage 1
    L1Args l1;
    l1.d[0] = {xw, w1T, h_w, 64, 2};
    l1.d[1] = {xa, a1T, h_a, 64, 0};
    l1.d[2] = {xv, v1T, h_v, 32, 0};
    l1.d[3] = {xg, g1T, h_g, 128, 3};
    lora1_kernel<<<dim3(16, 1, 4), 256, 0, stream>>>(l1);

    // 5) lora stage 2 + g2
    L2Args l2;
    l2.d[0] = {h_w, w2T, w0, dbuf, 64, 4};
    l2.d[1] = {h_a, a2T, a0, abuf, 64, 5};
    l2.d[2] = {h_v, v2T, v0, vbuf, 32, 6};
    l2.d[3] = {h_g, g2T, nullptr, gbuf, 128, 0};
    l2.vraw = vraw; l2.vfirst = v_first;
    lora2_kernel<<<dim3(16, 8, 4), 256, 0, stream>>>(l2);

    // 6) pack (contiguous PK blocks incl. r/d/bt/ct; writes scaled k back to kbuf)
    pack_kernel<<<BB * TT * HH / 4, 256, 0, stream>>>(kbuf, abuf, rbuf, vbuf, dbuf, k_k, k_a, PK);

    // 7) sequential recurrence (1 compute + 3 loader waves; 16 row-blocks per bh; writes ybuf)
    scan_kernel<<<BB * HH * 16, 256, 0, stream>>>(PK, ybuf);

    // 8) groupnorm + residual + gate (writes zbuf = dbuf region)
    gn_kernel<<<BB * TT * HH / 4, 256, 0, stream>>>(ybuf, rbuf, kbuf, vbuf, gbuf, ln_w, ln_b, r_k, zbuf);

    // 9) output projection -> d_out (f32)
    final_kernel<<<dim3(16, 8), 256, 0, stream>>>(zbuf, WoT, (float*)d_out);
}

// Round 5
// 426.267 us; speedup vs baseline: 1.7900x; 1.0127x over previous
//
#include <hip/hip_runtime.h>
#include <hip/hip_bf16.h>
#include <cstdint>
#include <cstddef>

typedef __hip_bfloat16 bf16;
typedef __bf16 bf16x8 __attribute__((ext_vector_type(8)));
typedef float f32x4 __attribute__((ext_vector_type(4)));

#define BB 2
#define TT 1024
#define CC 1024
#define HH 16
#define PKS 448   // floats per (bh,t) block: k[64] kk[64] bb[64] v[64] r[64] d[64] bt ct pad
#define PKB 1792  // bytes per block (448*4)
#define CH 8      // steps per chunk
#define NCH 4     // chunks in LDS ring
#define STEPB 2048  // bytes per step slot in LDS
#define CHB (CH * STEPB)
#define NC (TT / CH)

__device__ __forceinline__ bf16 f2b(float v){ return __float2bfloat16(v); }

// 16-lane-row sum via DPP only: xor1, xor2 (quad_perm), half_mirror (^4 after quads
// uniform), row_mirror (^8 after halves uniform). No DS pipe, no shuffles.
__device__ __forceinline__ float hex_add(float x) {
    x += __int_as_float(__builtin_amdgcn_mov_dpp(__float_as_int(x), 0xB1, 0xF, 0xF, true));  // quad_perm xor1
    x += __int_as_float(__builtin_amdgcn_mov_dpp(__float_as_int(x), 0x4E, 0xF, 0xF, true));  // quad_perm xor2
    x += __int_as_float(__builtin_amdgcn_mov_dpp(__float_as_int(x), 0x141, 0xF, 0xF, true)); // row_half_mirror (^4)
    x += __int_as_float(__builtin_amdgcn_mov_dpp(__float_as_int(x), 0x140, 0xF, 0xF, true)); // row_mirror (^8)
    return x;
}

// async global -> LDS, 16B per lane (dest = uniform base + lane*16, src per-lane)
typedef __attribute__((address_space(3))) void as3_void;
typedef __attribute__((address_space(1))) const void as1_void;
__device__ __forceinline__ void gload_lds16(const void* g, void* l) {
    __builtin_amdgcn_global_load_lds((as1_void*)g, (as3_void*)l, 16, 0, 0);
}

// ---------------- batched transpose+convert: f32 [R][S] -> bf16 [S][R] ----------------
struct TrDesc { const float* in; bf16* out; int R, S; };
struct TrArgs { TrDesc d[12]; };

__global__ __launch_bounds__(256) void transpose_batch(TrArgs args)
{
    TrDesc t = args.d[blockIdx.z];
    __shared__ float tile[32][33];
    int s0 = blockIdx.x * 32, r0 = blockIdx.y * 32;
    if (s0 >= t.S || r0 >= t.R) return;      // block-uniform early exit
    int tx = threadIdx.x & 31, ty = threadIdx.x >> 5;
#pragma unroll
    for (int i = 0; i < 4; i++) {
        int r = r0 + ty + i * 8, s = s0 + tx;
        if (r < t.R && s < t.S) tile[ty + i * 8][tx] = t.in[(size_t)r * t.S + s];
    }
    __syncthreads();
#pragma unroll
    for (int i = 0; i < 4; i++) {
        int s = s0 + ty + i * 8, r = r0 + tx;
        if (s < t.S && r < t.R) t.out[(size_t)s * t.R + r] = f2b(tile[tx][ty + i * 8]);
    }
}

// ---------------- token-shift mix (f32 in -> bf16 out) + v_first passthrough ----------------
__global__ __launch_bounds__(256) void mix_kernel(
    const float* __restrict__ x, const float* __restrict__ vfirst,
    const float* __restrict__ mr, const float* __restrict__ mw, const float* __restrict__ mk,
    const float* __restrict__ mv, const float* __restrict__ ma, const float* __restrict__ mg,
    bf16* __restrict__ xr, bf16* __restrict__ xw, bf16* __restrict__ xk,
    bf16* __restrict__ xv, bf16* __restrict__ xa, bf16* __restrict__ xg,
    float* __restrict__ vout)
{
    int row = blockIdx.x;
    int t = row & (TT - 1);
    size_t base = (size_t)row * CC;
    for (int c = threadIdx.x; c < CC; c += 256) {
        float xc = x[base + c];
        float xp = (t > 0) ? x[base - CC + c] : 0.f;
        float d = xp - xc;
        xr[base + c] = f2b(xc + d * mr[c]);
        xw[base + c] = f2b(xc + d * mw[c]);
        xk[base + c] = f2b(xc + d * mk[c]);
        xv[base + c] = f2b(xc + d * mv[c]);
        xa[base + c] = f2b(xc + d * ma[c]);
        xg[base + c] = f2b(xc + d * mg[c]);
        vout[base + c] = vfirst[base + c];   // exact f32 passthrough
    }
}

// ---------------- shared MFMA tile body: 128x128 tile of A[M,K] @ BT[N,K]^T ----------------
template <class EmitF>
__device__ __forceinline__ void gemm_tile(const bf16* __restrict__ A, const bf16* __restrict__ BT,
                                          int K, int m0, int n0, EmitF emit)
{
    __shared__ __align__(16) bf16 Atile[128 * 32];
    __shared__ __align__(16) bf16 Btile[128 * 32];
    int tid = threadIdx.x;
    int w = tid >> 6, lane = tid & 63;
    int wr = w >> 1, wc = w & 1;
    int quad = lane >> 4, l16 = lane & 15;

    f32x4 zero = {0.f, 0.f, 0.f, 0.f};
    f32x4 acc[4][4];
#pragma unroll
    for (int i = 0; i < 4; i++)
#pragma unroll
        for (int j = 0; j < 4; j++) acc[i][j] = zero;

    int rr = lane >> 2;            // 0..15
    int cs = lane & 3;             // chunk slot in LDS
    int ra0 = w * 32 + rr;         // rows this lane stages
    int ra1 = ra0 + 16;
    int cg0 = cs ^ ((ra0 >> 1) & 3);   // global chunk (XOR swizzle)
    int cg1 = cs ^ ((ra1 >> 1) & 3);

    for (int k0 = 0; k0 < K; k0 += 32) {
        uint4 av0 = *reinterpret_cast<const uint4*>(A  + (size_t)(m0 + ra0) * K + k0 + cg0 * 8);
        uint4 av1 = *reinterpret_cast<const uint4*>(A  + (size_t)(m0 + ra1) * K + k0 + cg1 * 8);
        uint4 bv0 = *reinterpret_cast<const uint4*>(BT + (size_t)(n0 + ra0) * K + k0 + cg0 * 8);
        uint4 bv1 = *reinterpret_cast<const uint4*>(BT + (size_t)(n0 + ra1) * K + k0 + cg1 * 8);
        __syncthreads();           // previous tile's reads complete
        *reinterpret_cast<uint4*>(&Atile[ra0 * 32 + cs * 8]) = av0;
        *reinterpret_cast<uint4*>(&Atile[ra1 * 32 + cs * 8]) = av1;
        *reinterpret_cast<uint4*>(&Btile[ra0 * 32 + cs * 8]) = bv0;
        *reinterpret_cast<uint4*>(&Btile[ra1 * 32 + cs * 8]) = bv1;
        __syncthreads();           // staging visible

        bf16x8 af[4], bfr[4];
#pragma unroll
        for (int mi = 0; mi < 4; mi++) {
            int m = wr * 64 + mi * 16 + l16;
            int c2 = quad ^ ((m >> 1) & 3);
            af[mi] = *reinterpret_cast<const bf16x8*>(&Atile[m * 32 + c2 * 8]);
        }
#pragma unroll
        for (int ni = 0; ni < 4; ni++) {
            int n = wc * 64 + ni * 16 + l16;
            int c2 = quad ^ ((n >> 1) & 3);
            bfr[ni] = *reinterpret_cast<const bf16x8*>(&Btile[n * 32 + c2 * 8]);
        }
#pragma unroll
        for (int mi = 0; mi < 4; mi++)
#pragma unroll
            for (int ni = 0; ni < 4; ni++)
                acc[mi][ni] = __builtin_amdgcn_mfma_f32_16x16x32_bf16(af[mi], bfr[ni], acc[mi][ni], 0, 0, 0);
    }

#pragma unroll
    for (int mi = 0; mi < 4; mi++)
#pragma unroll
        for (int ni = 0; ni < 4; ni++)
#pragma unroll
            for (int rg = 0; rg < 4; rg++) {
                int m = m0 + wr * 64 + mi * 16 + quad * 4 + rg;
                int n = n0 + wc * 64 + ni * 16 + l16;
                emit(m, n, acc[mi][ni][rg]);
            }
}

// ---------------- big projections r/k/v: z-batched, N=K=1024, f32 out ----------------
struct B3Args { const bf16* A[3]; const bf16* BT[3]; float* out[3]; };
__global__ __launch_bounds__(256) void big3_kernel(B3Args args)
{
    int z = blockIdx.z;
    float* out = args.out[z];
    gemm_tile(args.A[z], args.BT[z], 1024, blockIdx.x * 128, blockIdx.y * 128,
              [&](int m, int n, float v) { out[(size_t)m * 1024 + n] = v; });
}

// ---------------- lora stage 1: z-batched (different A per z), small N, bf16 out ----------------
struct L1Desc { const bf16* A; const bf16* BT; bf16* outB; int N; int mode; }; // mode: 0 plain, 2 tanh, 3 sigmoid
struct L1Args { L1Desc d[4]; };
__global__ __launch_bounds__(256) void lora1_kernel(L1Args args)
{
    L1Desc dz = args.d[blockIdx.z];
    gemm_tile(dz.A, dz.BT, 1024, blockIdx.x * 128, 0,
              [&](int m, int n, float v) {
                  if (n < dz.N) {
                      float r = (dz.mode == 2) ? tanhf(v)
                              : (dz.mode == 3) ? 1.f / (1.f + expf(-v)) : v;
                      dz.outB[(size_t)m * dz.N + n] = f2b(r);
                  }
              });
}

// ---------------- lora stage 2 (+g2): z-batched, N=1024, f32 out, fused epilogues ----------------
struct L2Desc { const bf16* A; const bf16* BT; const float* bias; float* outF; int K; int mode; };
struct L2Args { L2Desc d[4]; const float* vraw; const float* vfirst; };
__global__ __launch_bounds__(256) void lora2_kernel(L2Args args)
{
    L2Desc dz = args.d[blockIdx.z];
    gemm_tile(dz.A, dz.BT, dz.K, blockIdx.x * 128, blockIdx.y * 128,
              [&](int m, int n, float v) {
                  size_t idx = (size_t)m * 1024 + n;
                  if (dz.mode == 4) {
                      float xx = v + dz.bias[n];
                      float ww = -log1pf(expf(-xx)) - 0.5f;   // -softplus(-x) - 0.5
                      dz.outF[idx] = expf(-expf(ww));
                  } else if (dz.mode == 5) {
                      float xx = v + dz.bias[n];
                      dz.outF[idx] = 1.f / (1.f + expf(-xx));
                  } else if (dz.mode == 6) {
                      float gate = 1.f / (1.f + expf(-(v + dz.bias[n])));
                      float vr = args.vraw[idx];
                      dz.outF[idx] = vr + (args.vfirst[idx] - vr) * gate;
                  } else {
                      dz.outF[idx] = v;
                  }
              });
}

// ---------------- final output projection ----------------
__global__ __launch_bounds__(256) void final_kernel(const bf16* __restrict__ A, const bf16* __restrict__ BT,
                                                    float* __restrict__ out)
{
    gemm_tile(A, BT, 1024, blockIdx.x * 128, blockIdx.y * 128,
              [&](int m, int n, float v) { out[(size_t)m * 1024 + n] = v; });
}

// ---------------- pack: kk norm, k scale, r/d copy-in -> contiguous PK block per (bh,t) ----------------
// PK[bh][t] block (448 floats): k[0..63], kk[64..127], bb[128..191], v[192..255],
//                               r[256..319], d[320..383], bt@384, ct@385, pad
__global__ __launch_bounds__(256) void pack_kernel(
    float* __restrict__ k, const float* __restrict__ a, const float* __restrict__ r,
    const float* __restrict__ v, const float* __restrict__ dw,
    const float* __restrict__ kkw, const float* __restrict__ kaw,
    float* __restrict__ PK)
{
    int tid = threadIdx.x;
    int wave = tid >> 6, lane = tid & 63;
    int idx = blockIdx.x * 4 + wave;        // (b*TT+t)*HH + h
    size_t off = (size_t)idx * 64 + lane;
    int c = (idx & 15) * 64 + lane;
    float kraw = k[off];
    float av = a[off];
    float kkv = kraw * kkw[c];
    float s = kkv * kkv;
#pragma unroll
    for (int m = 32; m; m >>= 1) s += __shfl_xor(s, m);
    float kkn = kkv / fmaxf(sqrtf(s), 1e-12f);
    float ks = kraw * (1.f + (av - 1.f) * kaw[c]);
    k[off] = ks;                            // write-back for gn_kernel
    float bb = kkn * av;
    float rv = r[off];
    float dv = dw[off];
    float bt = bb * rv, ct = ks * rv;
#pragma unroll
    for (int m = 32; m; m >>= 1) { bt += __shfl_xor(bt, m); ct += __shfl_xor(ct, m); }
    int b = idx >> 14;                      // / (TT*HH)
    int h = idx & 15;
    int t = (idx >> 4) & (TT - 1);
    size_t sidx = (size_t)(b * HH + h) * TT + t;
    float* pw = PK + sidx * PKS;
    pw[lane] = ks; pw[64 + lane] = kkn; pw[128 + lane] = bb; pw[192 + lane] = v[off];
    pw[256 + lane] = rv; pw[320 + lane] = dv;
    if (lane == 0) { pw[384] = bt; pw[385] = ct; }
}

// ---------------- sequential state recurrence: producer/consumer, counted vmcnt ----------------
// Grid 512 = 32 bh x 16 row-blocks (XCD-grouped). Block = 256 threads = 4 waves:
// wave 0 computes, waves 1-3 stage 8-step chunks into a 4-chunk LDS ring via
// global_load_lds. KEY (round-4 fix): raw s_barrier + counted vmcnt(L) where L =
// loads issued THIS iteration -- the wait covers only the PREVIOUS iteration's
// chunk, whose latency was hidden under a full chunk of compute. __syncthreads()
// is not used in the loop (it drains vmcnt(0), exposing the just-issued loads).
// Ring invariant at iteration i: compute reads chunk i; i+1,i+2 resident; i+3 in
// flight into slot (i-1)&3 (fully consumed into registers before the last barrier).
struct SetR { f32x4 q, d, r, k, b; float vi; float2 bc; };

__device__ __forceinline__ void ds_load_set(SetR& s, const char* slot, int c16, int row)
{
    s.q  = *(const f32x4*)(slot + 256  + c16);   // kk
    s.d  = *(const f32x4*)(slot + 1280 + c16);   // decay
    s.r  = *(const f32x4*)(slot + 1024 + c16);   // r
    s.k  = *(const f32x4*)(slot + 0    + c16);   // k
    s.b  = *(const f32x4*)(slot + 512  + c16);   // bb
    s.vi = *(const float*)(slot + 768 + row * 4);
    s.bc = *(const float2*)(slot + 1536);
}

__device__ __forceinline__ float step4(const SetR& sd, f32x4& S)
{
    f32x4 Sd   = S * sd.d;
    f32x4 sacv = S * sd.q;
    f32x4 oacv = Sd * sd.r;
    float sar = (sacv[0] + sacv[1]) + (sacv[2] + sacv[3]);
    float od  = (oacv[0] + oacv[1]) + (oacv[2] + oacv[3]);
    sar = hex_add(sar);
    od  = hex_add(od);
    float sa = -sar;
    float o = fmaf(sd.vi, sd.bc.y, fmaf(sa, sd.bc.x, od));
    S = Sd + sa * sd.b + sd.vi * sd.k;
    return o;
}

__global__ __launch_bounds__(256, 1) void scan_kernel(
    const float* __restrict__ PK, float* __restrict__ ybuf)
{
    __shared__ __align__(16) char ring[NCH * CHB];   // 4 chunks x 8 steps x 2KB = 64KB
    const int tid = threadIdx.x;
    const int wid = tid >> 6, lane = tid & 63;
    // XCD-grouped bijective decode (grid 512): all 16 row-blocks of a head on one XCD.
    const int xcd = blockIdx.x & 7, kk = blockIdx.x >> 3;
    const int bh = xcd * 4 + (kk >> 4);      // 0..31
    const int wq = kk & 15;                  // row-block 0..15
    const int b = bh >> 4, h = bh & 15;
    const int row = wq * 4 + (lane >> 4);    // 0..63 (compute wave semantics)
    const int c = lane & 15;
    const int c16 = c * 16;

    const char* base = (const char*)(PK + (size_t)bh * TT * PKS);
    const char* g1 = base + lane * 16;          // bytes 0..1023 of each step block
    const char* g2 = g1 + 1024;                 // bytes 1024..2047 (tail waste benign)

    // loader lambda: wave wid (1..3) stages steps j = wid-1, wid-1+3, ... of chunk ci
    // loads issued per chunk: wid1=6, wid2=6, wid3=4
    auto stage_chunk = [&](int ci) {
        const char* p1 = g1 + (size_t)ci * CH * PKB;
        const char* p2 = g2 + (size_t)ci * CH * PKB;
        char* s = ring + (ci & (NCH - 1)) * CHB;
        for (int j = wid - 1; j < CH; j += 3) {
            gload_lds16(p1 + (size_t)j * PKB, s + j * STEPB);
            gload_lds16(p2 + (size_t)j * PKB, s + j * STEPB + 1024);
        }
    };

    if (wid > 0) {
        stage_chunk(0);
        stage_chunk(1);
        stage_chunk(2);
        asm volatile("s_waitcnt vmcnt(0)" ::: "memory");   // prologue: full drain once
    }
    __builtin_amdgcn_sched_barrier(0);
    __builtin_amdgcn_s_barrier();            // publishes chunks 0-2
    __builtin_amdgcn_sched_barrier(0);

    f32x4 S = {0.f, 0.f, 0.f, 0.f};
    SetR X, Y;
    if (wid == 0) ds_load_set(X, ring, c16, row);
    float* py = ybuf + (size_t)b * TT * CC + h * 64 + row;

    for (int i = 0; i < NC; i++) {
        if (wid == 0) {
            const char* sl  = ring + (i & (NCH - 1)) * CHB;
            const char* sln = ring + ((i + 1) & (NCH - 1)) * CHB;
            float o;
            // 8 steps, 2-set pipe: load next step's set, compute current.
            ds_load_set(Y, sl + 1 * STEPB, c16, row); o = step4(X, S); if (c == 0) *py = o; py += CC;
            ds_load_set(X, sl + 2 * STEPB, c16, row); o = step4(Y, S); if (c == 0) *py = o; py += CC;
            ds_load_set(Y, sl + 3 * STEPB, c16, row); o = step4(X, S); if (c == 0) *py = o; py += CC;
            ds_load_set(X, sl + 4 * STEPB, c16, row); o = step4(Y, S); if (c == 0) *py = o; py += CC;
            ds_load_set(Y, sl + 5 * STEPB, c16, row); o = step4(X, S); if (c == 0) *py = o; py += CC;
            ds_load_set(X, sl + 6 * STEPB, c16, row); o = step4(Y, S); if (c == 0) *py = o; py += CC;
            ds_load_set(Y, sl + 7 * STEPB, c16, row); o = step4(X, S); if (c == 0) *py = o; py += CC;
            ds_load_set(X, sln,            c16, row); o = step4(Y, S); if (c == 0) *py = o; py += CC;
            // (i == NC-1: the final ds_load_set reads stale slot data, never consumed)
        } else {
            if (i + 3 < NC) {
                stage_chunk(i + 3);
                // counted wait: covers chunk i+2 (issued last iteration, latency hidden
                // under a full chunk of compute); chunk i+3 stays in flight.
                if (wid == 3) asm volatile("s_waitcnt vmcnt(4)" ::: "memory");
                else          asm volatile("s_waitcnt vmcnt(6)" ::: "memory");
            } else {
                asm volatile("s_waitcnt vmcnt(0)" ::: "memory");   // epilogue drain (cheap)
            }
        }
        __builtin_amdgcn_sched_barrier(0);
        __builtin_amdgcn_s_barrier();        // publishes chunk i+2 (and older)
        __builtin_amdgcn_sched_barrier(0);
    }
}

// ---------------- groupnorm + residual + gate -> z (bf16), 4 heads/block ----------------
__global__ __launch_bounds__(256) void gn_kernel(
    const float* __restrict__ y, const float* __restrict__ r, const float* __restrict__ k,
    const float* __restrict__ v, const float* __restrict__ g,
    const float* __restrict__ lnw, const float* __restrict__ lnb,
    const float* __restrict__ rk, bf16* __restrict__ z)
{
    int tid = threadIdx.x;
    int idx = blockIdx.x * 4 + (tid >> 6);   // (b*T+t)*16 + h
    int lane = tid & 63;
    size_t off = (size_t)idx * 64 + lane;
    int c = (idx & 15) * 64 + lane;
    float yv = y[off];
    float rv = r[off], kv = k[off], vv = v[off];
    float s1 = yv, s2 = yv * yv, s3 = rv * kv * rk[c];
#pragma unroll
    for (int m = 32; m; m >>= 1) {
        s1 += __shfl_xor(s1, m);
        s2 += __shfl_xor(s2, m);
        s3 += __shfl_xor(s3, m);
    }
    float mu = s1 * (1.f / 64.f);
    float var = fmaxf(s2 * (1.f / 64.f) - mu * mu, 0.f);
    float yn = (yv - mu) * rsqrtf(var + 64e-5f) * lnw[c] + lnb[c];
    float out = (yn + s3 * vv) * g[off];
    z[off] = f2b(out);
}

// ---------------- host ----------------
extern "C" void kernel_launch(void* const* d_in, const int* in_sizes, int n_in,
                              void* d_out, int out_size, void* d_ws, size_t ws_size,
                              hipStream_t stream)
{
    const float* x       = (const float*)d_in[0];
    const float* v_first = (const float*)d_in[1];
    const float* x_r = (const float*)d_in[2];
    const float* x_w = (const float*)d_in[3];
    const float* x_k = (const float*)d_in[4];
    const float* x_v = (const float*)d_in[5];
    const float* x_a = (const float*)d_in[6];
    const float* x_g = (const float*)d_in[7];
    const float* w1 = (const float*)d_in[8];
    const float* w2 = (const float*)d_in[9];
    const float* w0 = (const float*)d_in[10];
    const float* a1 = (const float*)d_in[11];
    const float* a2 = (const float*)d_in[12];
    const float* a0 = (const float*)d_in[13];
    const float* v1 = (const float*)d_in[14];
    const float* v2 = (const float*)d_in[15];
    const float* v0 = (const float*)d_in[16];
    const float* g1 = (const float*)d_in[17];
    const float* g2 = (const float*)d_in[18];
    const float* k_k = (const float*)d_in[19];
    const float* k_a = (const float*)d_in[20];
    const float* r_k = (const float*)d_in[21];
    const float* W_r = (const float*)d_in[22];
    const float* W_k = (const float*)d_in[23];
    const float* W_v = (const float*)d_in[24];
    const float* W_o = (const float*)d_in[25];
    const float* ln_w = (const float*)d_in[26];
    const float* ln_b = (const float*)d_in[27];

    const size_t BTC = (size_t)BB * TT * CC;   // 2M
    const int M = BB * TT;                     // 2048

    char* ws = (char*)d_ws;
    size_t off = 0;
    auto alloc = [&](size_t bytes) -> char* {
        char* p = ws + off;
        off += (bytes + 255) & ~(size_t)255;
        return p;
    };

    // ---- region0: everything here is dead before pack_kernel; PK aliases it ----
    bf16* xr = (bf16*)alloc(BTC * 2);
    bf16* xw = (bf16*)alloc(BTC * 2);
    bf16* xk = (bf16*)alloc(BTC * 2);
    bf16* xv = (bf16*)alloc(BTC * 2);
    bf16* xa = (bf16*)alloc(BTC * 2);
    bf16* xg = (bf16*)alloc(BTC * 2);
    bf16* WrT = (bf16*)alloc(1024 * 1024 * 2);
    bf16* WkT = (bf16*)alloc(1024 * 1024 * 2);
    bf16* WvT = (bf16*)alloc(1024 * 1024 * 2);
    bf16* w1T = (bf16*)alloc(128 * 1024 * 2);   // 64 rows used, pad benign
    bf16* a1T = (bf16*)alloc(128 * 1024 * 2);
    bf16* v1T = (bf16*)alloc(128 * 1024 * 2);   // 32 rows used
    bf16* g1T = (bf16*)alloc(128 * 1024 * 2);
    bf16* w2T = (bf16*)alloc(1024 * 64 * 2);
    bf16* a2T = (bf16*)alloc(1024 * 64 * 2);
    bf16* v2T = (bf16*)alloc(1024 * 32 * 2);
    bf16* g2T = (bf16*)alloc(1024 * 128 * 2);
    bf16* h_w = (bf16*)alloc((size_t)M * 64 * 2);
    bf16* h_a = (bf16*)alloc((size_t)M * 64 * 2);
    bf16* h_v = (bf16*)alloc((size_t)M * 32 * 2);
    bf16* h_g = (bf16*)alloc((size_t)M * 128 * 2);

    // PK aliases region0 (~57.3 MB); continue past max(region0, PK)
    float* PK = (float*)ws;
    size_t pk_end = (size_t)BB * HH * TT * PKS * 4;   // 58,720,256
    if (off < pk_end) off = pk_end;
    off = (off + 255) & ~(size_t)255;

    // ---- live across pack/scan ----
    bf16* WoT = (bf16*)alloc(1024 * 1024 * 2);
    float* rbuf = (float*)alloc(BTC * 4);
    float* kbuf = (float*)alloc(BTC * 4);
    float* vraw = (float*)alloc(BTC * 4);   // reused as ybuf after lora2
    float* vbuf = (float*)alloc(BTC * 4);
    float* dbuf = (float*)alloc(BTC * 4);   // reused as zbuf (bf16) after scan
    float* abuf = (float*)alloc(BTC * 4);
    float* gbuf = (float*)alloc(BTC * 4);

    float* ybuf = vraw;
    bf16*  zbuf = (bf16*)dbuf;

    (void)in_sizes; (void)n_in; (void)out_size; (void)ws_size;

    // 1) all weight transposes in one launch
    TrArgs ta;
    ta.d[0]  = {W_r, WrT, 1024, 1024};
    ta.d[1]  = {W_k, WkT, 1024, 1024};
    ta.d[2]  = {W_v, WvT, 1024, 1024};
    ta.d[3]  = {W_o, WoT, 1024, 1024};
    ta.d[4]  = {w1, w1T, 1024, 64};
    ta.d[5]  = {a1, a1T, 1024, 64};
    ta.d[6]  = {v1, v1T, 1024, 32};
    ta.d[7]  = {g1, g1T, 1024, 128};
    ta.d[8]  = {w2, w2T, 64, 1024};
    ta.d[9]  = {a2, a2T, 64, 1024};
    ta.d[10] = {v2, v2T, 32, 1024};
    ta.d[11] = {g2, g2T, 128, 1024};
    transpose_batch<<<dim3(32, 32, 12), 256, 0, stream>>>(ta);

    // 2) token-shift mix (+ v_first passthrough)
    float* vout = (float*)d_out + BTC;
    mix_kernel<<<BB * TT, 256, 0, stream>>>(x, v_first, x_r, x_w, x_k, x_v, x_a, x_g,
                                            xr, xw, xk, xv, xa, xg, vout);

    // 3) big projections r/k/v
    B3Args b3;
    b3.A[0] = xr; b3.A[1] = xk; b3.A[2] = xv;
    b3.BT[0] = WrT; b3.BT[1] = WkT; b3.BT[2] = WvT;
    b3.out[0] = rbuf; b3.out[1] = kbuf; b3.out[2] = vraw;
    big3_kernel<<<dim3(16, 8, 3), 256, 0, stream>>>(b3);

    // 4) lora stage 1
    L1Args l1;
    l1.d[0] = {xw, w1T, h_w, 64, 2};
    l1.d[1] = {xa, a1T, h_a, 64, 0};
    l1.d[2] = {xv, v1T, h_v, 32, 0};
    l1.d[3] = {xg, g1T, h_g, 128, 3};
    lora1_kernel<<<dim3(16, 1, 4), 256, 0, stream>>>(l1);

    // 5) lora stage 2 + g2
    L2Args l2;
    l2.d[0] = {h_w, w2T, w0, dbuf, 64, 4};
    l2.d[1] = {h_a, a2T, a0, abuf, 64, 5};
    l2.d[2] = {h_v, v2T, v0, vbuf, 32, 6};
    l2.d[3] = {h_g, g2T, nullptr, gbuf, 128, 0};
    l2.vraw = vraw; l2.vfirst = v_first;
    lora2_kernel<<<dim3(16, 8, 4), 256, 0, stream>>>(l2);

    // 6) pack (contiguous PK blocks incl. r/d/bt/ct; writes scaled k back to kbuf)
    pack_kernel<<<BB * TT * HH / 4, 256, 0, stream>>>(kbuf, abuf, rbuf, vbuf, dbuf, k_k, k_a, PK);

    // 7) sequential recurrence (1 compute + 3 loader waves, counted vmcnt; writes ybuf)
    scan_kernel<<<BB * HH * 16, 256, 0, stream>>>(PK, ybuf);

    // 8) groupnorm + residual + gate (writes zbuf = dbuf region)
    gn_kernel<<<BB * TT * HH / 4, 256, 0, stream>>>(ybuf, rbuf, kbuf, vbuf, gbuf, ln_w, ln_b, r_k, zbuf);

    // 9) output projection -> d_out (f32)
    final_kernel<<<dim3(16, 8), 256, 0, stream>>>(zbuf, WoT, (float*)d_out);
}